// Round 3
// baseline (11122.029 us; speedup 1.0000x reference)
//
#include <hip/hip_runtime.h>
#include <math.h>

#define NIT 200
#define NN 128
#define TI 4
#define TJ 4
#define GI 32   // NN/TI
#define GJ 32   // NN/TJ
#define NTHREADS 1024
#define NWAVES 16
#define DTOT 16384.0f

__global__ __launch_bounds__(NTHREADS, 1)
void tv_kernel(const float* __restrict__ Min, const float* __restrict__ tvr,
               float* __restrict__ out, int Nb)
{
  const float MUc = 0.25f;
  const int b   = blockIdx.x;
  const int tid = threadIdx.x;
  const int tx  = tid & (GJ - 1);   // 0..31
  const int ty  = tid >> 5;         // 0..31
  const int lane = tid & 63;
  const int wv   = tid >> 6;
  const int i0 = ty * TI;
  const int j0 = tx * TJ;

  // [buf][comp-row][ty][tx] -> bank = tx%32, 2-way broadcast-free
  __shared__ float  sTop [2][TJ][GI][GJ];   // 32 KB
  __shared__ float  sLeft[2][TI][GI][GJ];   // 32 KB
  __shared__ float4 sRedA[2][NWAVES];
  __shared__ float2 sRedB[2][NWAVES];

  const float r = tvr[0];

  // register state: 6 arrays x 16 = 96 floats
  float m[TI][TJ], ux[TI][TJ], uy[TI][TJ], xx[TI][TJ], xy[TI][TJ], t[TI][TJ];

  const float* Mb = Min + (size_t)b * NN * NN;
#pragma unroll
  for (int di = 0; di < TI; ++di) {
    float4 v4 = *reinterpret_cast<const float4*>(Mb + (i0 + di) * NN + j0);
    m[di][0] = v4.x; m[di][1] = v4.y; m[di][2] = v4.z; m[di][3] = v4.w;
#pragma unroll
    for (int dj = 0; dj < TJ; ++dj) {
      ux[di][dj] = 0.f; uy[di][dj] = 0.f;
      xx[di][dj] = 0.f; xy[di][dj] = 0.f;
      t[di][dj] = 0.f;
    }
  }

  int par = 0;
  // block reduce: 2 lane-sums + 2 wave-uniform counts -> (sum0,cnt0,sum1,cnt1)
  auto red4 = [&](float s0, int c0, float s1, int c1) -> float4 {
#pragma unroll
    for (int off = 32; off >= 1; off >>= 1) {
      s0 += __shfl_xor(s0, off);
      s1 += __shfl_xor(s1, off);
    }
    if (lane == 0) sRedA[par][wv] = make_float4(s0, (float)c0, s1, (float)c1);
    __syncthreads();
    float4 q = sRedA[par][lane & (NWAVES - 1)];
#pragma unroll
    for (int off = 1; off < NWAVES; off <<= 1) {
      q.x += __shfl_xor(q.x, off); q.y += __shfl_xor(q.y, off);
      q.z += __shfl_xor(q.z, off); q.w += __shfl_xor(q.w, off);
    }
    par ^= 1;
    return q;
  };
  // block reduce: 4 lane-sums + 2 wave-uniform counts
  auto red6 = [&](float s0, float s1, float p0, float p1, int c0, int c1,
                  float4& o4, float2& o2) {
#pragma unroll
    for (int off = 32; off >= 1; off >>= 1) {
      s0 += __shfl_xor(s0, off); s1 += __shfl_xor(s1, off);
      p0 += __shfl_xor(p0, off); p1 += __shfl_xor(p1, off);
    }
    if (lane == 0) {
      sRedA[par][wv] = make_float4(s0, s1, p0, p1);
      sRedB[par][wv] = make_float2((float)c0, (float)c1);
    }
    __syncthreads();
    float4 q  = sRedA[par][lane & (NWAVES - 1)];
    float2 w2 = sRedB[par][lane & (NWAVES - 1)];
#pragma unroll
    for (int off = 1; off < NWAVES; off <<= 1) {
      q.x  += __shfl_xor(q.x, off);  q.y  += __shfl_xor(q.y, off);
      q.z  += __shfl_xor(q.z, off);  q.w  += __shfl_xor(q.w, off);
      w2.x += __shfl_xor(w2.x, off); w2.y += __shfl_xor(w2.y, off);
    }
    par ^= 1;
    o4 = q; o2 = w2;
  };

  // Duchi threshold via Newton on shifted form: tn = t + (Sum max(a-t,0) - rad)/cnt.
  // Probe (psa,pc at tp) comes pre-reduced from the fused pass. Exact fixed point.
  auto solve2 = [&](auto&& scan, float S0, float S1, float rad,
                    float psa0, float pc0, float tp0,
                    float psa1, float pc1, float tp1) -> float2 {
    const float invD = 1.0f / DTOT;
    float t0, t1; bool d0 = false, d1 = false;
    if (S0 <= rad) { t0 = 0.f; d0 = true; }
    else {
      float lb = (S0 - rad) * invD;
      if (pc0 < 0.5f) t0 = lb;
      else {
        float tn = tp0 + __fdividef(psa0 - rad, pc0);
        if (tn == tp0) { t0 = tn; d0 = true; }
        else t0 = fmaxf(tn, lb);
      }
    }
    if (S1 <= rad) { t1 = 0.f; d1 = true; }
    else {
      float lb = (S1 - rad) * invD;
      if (pc1 < 0.5f) t1 = lb;
      else {
        float tn = tp1 + __fdividef(psa1 - rad, pc1);
        if (tn == tp1) { t1 = tn; d1 = true; }
        else t1 = fmaxf(tn, lb);
      }
    }
    for (int k = 0; k < 30 && !(d0 && d1); ++k) {
      float sa0 = 0.f, sa1 = 0.f; int cn0 = 0, cn1 = 0;
      scan(t0, t1, sa0, cn0, sa1, cn1);
      float4 rd = red4(sa0, cn0, sa1, cn1);
      if (!d0) {
        if (rd.y < 0.5f) t0 = (S0 - rad) * invD;
        else {
          float tn = t0 + __fdividef(rd.x - rad, rd.y);
          if (tn == t0) d0 = true;
          t0 = tn;
        }
      }
      if (!d1) {
        if (rd.w < 0.5f) t1 = (S1 - rad) * invD;
        else {
          float tn = t1 + __fdividef(rd.z - rad, rd.w);
          if (tn == t1) d1 = true;
          t1 = tn;
        }
      }
    }
    return make_float2(t0, t1);
  };

  auto scanP1 = [&](float t0, float t1, float& sa0, int& cn0, float& sa1, int& cn1) {
#pragma unroll
    for (int di = 0; di < TI; ++di)
#pragma unroll
      for (int dj = 0; dj < TJ; ++dj) {
        float e0 = fabsf(ux[di][dj] - xx[di][dj]) - t0;
        float e1 = fabsf(uy[di][dj] - xy[di][dj]) - t1;
        sa0 += fmaxf(e0, 0.f); sa1 += fmaxf(e1, 0.f);
        cn0 += (int)__popcll(__ballot(e0 > 0.f));
        cn1 += (int)__popcll(__ballot(e1 > 0.f));
      }
  };
  auto scanP3 = [&](float t0, float t1, float& sa0, int& cn0, float& sa1, int& cn1) {
#pragma unroll
    for (int di = 0; di < TI; ++di)
#pragma unroll
      for (int dj = 0; dj < TJ; ++dj) {
        float e0 = fabsf(ux[di][dj]) - t0;
        float e1 = fabsf(uy[di][dj]) - t1;
        sa0 += fmaxf(e0, 0.f); sa1 += fmaxf(e1, 0.f);
        cn0 += (int)__popcll(__ballot(e0 > 0.f));
        cn1 += (int)__popcll(__ballot(e1 > 0.f));
      }
  };

  // t = m - div(ux,uy); reads buf0 halos, writes t halos to buf1
  auto div_pass = [&]() {
#pragma unroll
    for (int di = 0; di < TI; ++di) {
      const int i = i0 + di;
#pragma unroll
      for (int dj = 0; dj < TJ; ++dj) {
        const int j = j0 + dj;
        float up, lf;
        if (di > 0) up = ux[di - 1][dj];
        else { float h = sTop[0][dj][(ty > 0) ? ty - 1 : 0][tx]; up = (ty > 0) ? h : 0.f; }
        if (dj > 0) lf = uy[di][dj - 1];
        else { float h = sLeft[0][di][ty][(tx > 0) ? tx - 1 : 0]; lf = (tx > 0) ? h : 0.f; }
        float vx = (i == NN - 1) ? 0.f : ux[di][dj];
        float vy = (j == NN - 1) ? 0.f : uy[di][dj];
        float tt = m[di][dj] - ((vx - up) + (vy - lf));
        t[di][dj] = tt;
        if (di == 0) sTop[1][dj][ty][tx] = tt;
        if (dj == 0) sLeft[1][di][ty][tx] = tt;
      }
    }
  };

  // reads buf1 halos; consume(di,dj,gx,gy) with (gx,gy)=grad(t)
  auto grad_pass = [&](auto&& consume) {
#pragma unroll
    for (int di = 0; di < TI; ++di) {
      const int i = i0 + di;
#pragma unroll
      for (int dj = 0; dj < TJ; ++dj) {
        const int j = j0 + dj;
        float dn, rt;
        if (di < TI - 1) dn = t[di + 1][dj];
        else dn = sTop[1][dj][(ty < GI - 1) ? ty + 1 : ty][tx];
        if (dj < TJ - 1) rt = t[di][dj + 1];
        else rt = sLeft[1][di][ty][(tx < GJ - 1) ? tx + 1 : tx];
        float gx = (i == NN - 1) ? 0.f : dn - t[di][dj];
        float gy = (j == NN - 1) ? 0.f : rt - t[di][dj];
        consume(di, dj, gx, gy);
      }
    }
  };

  float A = 0.f;
  // P1 carry: sums + probe results produced at previous P4b
  float S0p = 0.f, S1p = 0.f, p1sa0 = 0.f, p1sa1 = 0.f, p1c0 = 0.f, p1c1 = 0.f;
  float t1p0 = 0.f, t1p1 = 0.f;
  float h1x = 0.f, h1y = 0.f, h3x = 0.f, h3y = 0.f;  // previous thresholds (warm starts)
  const float rad3 = r * (MUc * 0.5f);

#pragma unroll 1
  for (int it = 0; it < NIT; ++it) {
    const float a_ = 0.5f * (MUc + sqrtf(MUc * (MUc + 4.f * A)));
    float thx, thy;
    if (it == 0) { thx = INFINITY; thy = INFINITY; }
    else {
      float2 th = solve2(scanP1, S0p, S1p, r * A, p1sa0, p1c0, t1p0, p1sa1, p1c1, t1p1);
      thx = th.x; thy = th.y;
      h1x = thx; h1y = thy;
    }

    // P2a: y = cu*u + cv*clamp(u-xi, ±th); write y halos (buf0)
    {
      const float inv = 1.f / (A + a_);
      const float cu = A * inv, cv = a_ * inv;
#pragma unroll
      for (int di = 0; di < TI; ++di)
#pragma unroll
        for (int dj = 0; dj < TJ; ++dj) {
          float vx = fminf(fmaxf(ux[di][dj] - xx[di][dj], -thx), thx);
          float vy = fminf(fmaxf(uy[di][dj] - xy[di][dj], -thy), thy);
          ux[di][dj] = ux[di][dj] * cu + vx * cv;
          uy[di][dj] = uy[di][dj] * cu + vy * cv;
        }
#pragma unroll
      for (int dj = 0; dj < TJ; ++dj) sTop[0][dj][ty][tx] = ux[TI - 1][dj];
#pragma unroll
      for (int di = 0; di < TI; ++di) sLeft[0][di][ty][tx] = uy[di][TJ - 1];
    }
    __syncthreads();
    div_pass();            // t = M - div(y)
    __syncthreads();

    // P2b: u_pre = y - (mu/2) grad(t); fused S3 sums + P3 probe at prev theta3
    const float t3p0 = fmaxf(0.f, h3x);
    const float t3p1 = fmaxf(0.f, h3y);
    {
      float s0 = 0.f, s1 = 0.f, p0 = 0.f, p1v = 0.f; int c0 = 0, c1 = 0;
      grad_pass([&](int di, int dj, float gx, float gy) {
        float nux = ux[di][dj] - 0.125f * gx;
        float nuy = uy[di][dj] - 0.125f * gy;
        ux[di][dj] = nux; uy[di][dj] = nuy;
        float a0 = fabsf(nux), a1 = fabsf(nuy);
        s0 += a0; s1 += a1;
        float e0 = a0 - t3p0, e1 = a1 - t3p1;
        p0 += fmaxf(e0, 0.f); p1v += fmaxf(e1, 0.f);
        c0 += (int)__popcll(__ballot(e0 > 0.f));
        c1 += (int)__popcll(__ballot(e1 > 0.f));
      });
      float4 q4; float2 q2;
      red6(s0, s1, p0, p1v, c0, c1, q4, q2);
      float2 th3 = solve2(scanP3, q4.x, q4.y, rad3, q4.z, q2.x, t3p0, q4.w, q2.y, t3p1);
      h3x = th3.x; h3y = th3.y;
      // P4a: u = clamp(u_pre, ±th3); write u halos (buf0)
#pragma unroll
      for (int di = 0; di < TI; ++di)
#pragma unroll
        for (int dj = 0; dj < TJ; ++dj) {
          ux[di][dj] = fminf(fmaxf(ux[di][dj], -th3.x), th3.x);
          uy[di][dj] = fminf(fmaxf(uy[di][dj], -th3.y), th3.y);
        }
#pragma unroll
      for (int dj = 0; dj < TJ; ++dj) sTop[0][dj][ty][tx] = ux[TI - 1][dj];
#pragma unroll
      for (int di = 0; di < TI; ++di) sLeft[0][di][ty][tx] = uy[di][TJ - 1];
    }
    __syncthreads();
    div_pass();            // t = Mnew
    __syncthreads();

    // P4b: xi += a*grad(Mnew); fused next-P1 sums + probe at prev theta1
    t1p0 = fmaxf(0.f, h1x);
    t1p1 = fmaxf(0.f, h1y);
    {
      float s0 = 0.f, s1 = 0.f, p0 = 0.f, p1v = 0.f; int c0 = 0, c1 = 0;
      grad_pass([&](int di, int dj, float gx, float gy) {
        xx[di][dj] += a_ * gx;
        xy[di][dj] += a_ * gy;
        float awx = fabsf(ux[di][dj] - xx[di][dj]);
        float awy = fabsf(uy[di][dj] - xy[di][dj]);
        s0 += awx; s1 += awy;
        float e0 = awx - t1p0, e1 = awy - t1p1;
        p0 += fmaxf(e0, 0.f); p1v += fmaxf(e1, 0.f);
        c0 += (int)__popcll(__ballot(e0 > 0.f));
        c1 += (int)__popcll(__ballot(e1 > 0.f));
      });
      float4 q4; float2 q2;
      red6(s0, s1, p0, p1v, c0, c1, q4, q2);
      S0p = q4.x; S1p = q4.y; p1sa0 = q4.z; p1sa1 = q4.w; p1c0 = q2.x; p1c1 = q2.y;
    }
    A += a_;
  }

  // outputs: M1 = last Mnew (in t), u interleaved (last-dim 2)
  float* outM = out + (size_t)b * NN * NN;
  float* outU = out + (size_t)Nb * NN * NN + (size_t)b * NN * NN * 2;
#pragma unroll
  for (int di = 0; di < TI; ++di)
#pragma unroll
    for (int dj = 0; dj < TJ; ++dj) {
      const int idx = (i0 + di) * NN + (j0 + dj);
      outM[idx] = t[di][dj];
      reinterpret_cast<float2*>(outU)[idx] = make_float2(ux[di][dj], uy[di][dj]);
    }
}

extern "C" void kernel_launch(void* const* d_in, const int* in_sizes, int n_in,
                              void* d_out, int out_size, void* d_ws, size_t ws_size,
                              hipStream_t stream) {
  const float* M  = (const float*)d_in[0];
  const float* tv = (const float*)d_in[1];
  const int Nb = in_sizes[0] / (NN * NN);   // 8
  tv_kernel<<<dim3(Nb), dim3(NTHREADS), 0, stream>>>(M, tv, (float*)d_out, Nb);
}

// Round 4
// 5773.722 us; speedup vs baseline: 1.9263x; 1.9263x over previous
//
#include <hip/hip_runtime.h>
#include <math.h>

#define NIT 200
#define NN 128
#define TI 4
#define TJ 8
#define GI 32   // NN/TI
#define GJ 16   // NN/TJ
#define NTHREADS 512
#define NWAVES 8
#define DTOT 16384.0f

// wave64 sum via DPP (canonical GCN sequence); valid in lane 63.
__device__ __forceinline__ float wsum(float x) {
  int v;
  v = __builtin_amdgcn_update_dpp(0, __float_as_int(x), 0x111, 0xf, 0xf, true); x += __int_as_float(v); // row_shr:1
  v = __builtin_amdgcn_update_dpp(0, __float_as_int(x), 0x112, 0xf, 0xf, true); x += __int_as_float(v); // row_shr:2
  v = __builtin_amdgcn_update_dpp(0, __float_as_int(x), 0x114, 0xf, 0xf, true); x += __int_as_float(v); // row_shr:4
  v = __builtin_amdgcn_update_dpp(0, __float_as_int(x), 0x118, 0xf, 0xf, true); x += __int_as_float(v); // row_shr:8
  v = __builtin_amdgcn_update_dpp(0, __float_as_int(x), 0x142, 0xa, 0xf, true); x += __int_as_float(v); // row_bcast:15
  v = __builtin_amdgcn_update_dpp(0, __float_as_int(x), 0x143, 0xc, 0xf, true); x += __int_as_float(v); // row_bcast:31
  return x;
}

__global__ __attribute__((amdgpu_flat_work_group_size(NTHREADS, NTHREADS),
                          amdgpu_waves_per_eu(2, 2)))
void tv_kernel(const float* __restrict__ Min, const float* __restrict__ tvr,
               float* __restrict__ out, int Nb)
{
  const float MUc = 0.25f;
  const int b   = blockIdx.x;
  const int tid = threadIdx.x;
  const int tx  = tid & (GJ - 1);   // 0..15
  const int ty  = tid >> 4;         // 0..31
  const int lane = tid & 63;
  const int wv   = tid >> 6;
  const int i0 = ty * TI;
  const int j0 = tx * TJ;

  // [buf][comp-row][ty][tx] -> bank = (ty*16+tx)%32, 2-way broadcast-free
  __shared__ float  sTop [2][TJ][GI][GJ];   // 32 KB
  __shared__ float  sLeft[2][TI][GI][GJ];   // 16 KB
  __shared__ float4 sRedA[2][NWAVES];
  __shared__ float2 sRedB[2][NWAVES];

  const float r = tvr[0];

  // register state: 6 arrays x 32 = 192 floats (waves_per_eu(2,2) -> arch VGPRs)
  float m[TI][TJ], ux[TI][TJ], uy[TI][TJ], xx[TI][TJ], xy[TI][TJ], t[TI][TJ];

  const float* Mb = Min + (size_t)b * NN * NN;
#pragma unroll
  for (int di = 0; di < TI; ++di) {
    float4 v0 = *reinterpret_cast<const float4*>(Mb + (i0 + di) * NN + j0);
    float4 v1 = *reinterpret_cast<const float4*>(Mb + (i0 + di) * NN + j0 + 4);
    m[di][0] = v0.x; m[di][1] = v0.y; m[di][2] = v0.z; m[di][3] = v0.w;
    m[di][4] = v1.x; m[di][5] = v1.y; m[di][6] = v1.z; m[di][7] = v1.w;
#pragma unroll
    for (int dj = 0; dj < TJ; ++dj) {
      ux[di][dj] = 0.f; uy[di][dj] = 0.f;
      xx[di][dj] = 0.f; xy[di][dj] = 0.f;
      t[di][dj] = 0.f;
    }
  }

  int par = 0;
  // block reduce: 2 float sums + 2 wave-uniform int counts
  auto redF2C2 = [&](float s0, float s1, int c0, int c1) -> float4 {
    s0 = wsum(s0); s1 = wsum(s1);
    if (lane == 63) sRedA[par][wv] = make_float4(s0, s1, (float)c0, (float)c1);
    __syncthreads();
    float4 acc = sRedA[par][0];
#pragma unroll
    for (int w = 1; w < NWAVES; ++w) {
      float4 q = sRedA[par][w];
      acc.x += q.x; acc.y += q.y; acc.z += q.z; acc.w += q.w;
    }
    par ^= 1;
    return acc;
  };
  // block reduce: 4 float sums + 2 wave-uniform int counts
  auto redF4C2 = [&](float s0, float s1, float p0, float p1, int c0, int c1,
                     float4& o4, float2& o2) {
    s0 = wsum(s0); s1 = wsum(s1); p0 = wsum(p0); p1 = wsum(p1);
    if (lane == 63) {
      sRedA[par][wv] = make_float4(s0, s1, p0, p1);
      sRedB[par][wv] = make_float2((float)c0, (float)c1);
    }
    __syncthreads();
    float4 a4 = sRedA[par][0]; float2 a2 = sRedB[par][0];
#pragma unroll
    for (int w = 1; w < NWAVES; ++w) {
      float4 q = sRedA[par][w]; float2 h = sRedB[par][w];
      a4.x += q.x; a4.y += q.y; a4.z += q.z; a4.w += q.w;
      a2.x += h.x; a2.y += h.y;
    }
    par ^= 1;
    o4 = a4; o2 = a2;
  };

  // Duchi threshold, shifted-Newton: tn = t + (Sum max(a-t,0) - rad)/cnt.
  // Terminates on exact fixed point (tn==t) OR segment stability (count
  // unchanged between successive evaluations -> Newton step is exact).
  auto solve2 = [&](auto&& scan, float S0, float S1, float rad,
                    float psa0, float pc0, float tp0,
                    float psa1, float pc1, float tp1) -> float2 {
    const float invD = 1.0f / DTOT;
    float t0, t1; bool d0 = false, d1 = false;
    float cp0 = -1.f, cp1 = -1.f;
    if (S0 <= rad) { t0 = 0.f; d0 = true; }
    else {
      float lb = (S0 - rad) * invD;
      if (pc0 < 0.5f) t0 = lb;
      else {
        float tn = tp0 + __fdividef(psa0 - rad, pc0);
        if (tn == tp0) { t0 = tn; d0 = true; }
        else { t0 = fmaxf(tn, lb); cp0 = pc0; }
      }
    }
    if (S1 <= rad) { t1 = 0.f; d1 = true; }
    else {
      float lb = (S1 - rad) * invD;
      if (pc1 < 0.5f) t1 = lb;
      else {
        float tn = tp1 + __fdividef(psa1 - rad, pc1);
        if (tn == tp1) { t1 = tn; d1 = true; }
        else { t1 = fmaxf(tn, lb); cp1 = pc1; }
      }
    }
    for (int k = 0; k < 24 && !(d0 && d1); ++k) {
      float sa0 = 0.f, sa1 = 0.f; int c0 = 0, c1 = 0;
      scan(t0, t1, sa0, c0, sa1, c1);
      float4 rd = redF2C2(sa0, sa1, c0, c1);  // (sum0, sum1, cnt0, cnt1)
      if (!d0) {
        if (rd.z < 0.5f) { t0 = (S0 - rad) * invD; cp0 = -1.f; }
        else {
          float tn = t0 + __fdividef(rd.x - rad, rd.z);
          if (tn == t0 || rd.z == cp0) d0 = true;
          t0 = tn; cp0 = rd.z;
        }
      }
      if (!d1) {
        if (rd.w < 0.5f) { t1 = (S1 - rad) * invD; cp1 = -1.f; }
        else {
          float tn = t1 + __fdividef(rd.z == rd.z ? rd.y - rad : 0.f, rd.w); // rd.y - rad over cnt1
          if (tn == t1 || rd.w == cp1) d1 = true;
          t1 = tn; cp1 = rd.w;
        }
      }
    }
    return make_float2(t0, t1);
  };

  auto scanP1 = [&](float t0, float t1, float& sa0, int& c0, float& sa1, int& c1) {
#pragma unroll
    for (int di = 0; di < TI; ++di)
#pragma unroll
      for (int dj = 0; dj < TJ; ++dj) {
        float e0 = fabsf(ux[di][dj] - xx[di][dj]) - t0;
        float e1 = fabsf(uy[di][dj] - xy[di][dj]) - t1;
        sa0 += fmaxf(e0, 0.f); sa1 += fmaxf(e1, 0.f);
        c0 += (int)__popcll(__ballot(e0 > 0.f));
        c1 += (int)__popcll(__ballot(e1 > 0.f));
      }
  };
  auto scanP3 = [&](float t0, float t1, float& sa0, int& c0, float& sa1, int& c1) {
#pragma unroll
    for (int di = 0; di < TI; ++di)
#pragma unroll
      for (int dj = 0; dj < TJ; ++dj) {
        float e0 = fabsf(ux[di][dj]) - t0;
        float e1 = fabsf(uy[di][dj]) - t1;
        sa0 += fmaxf(e0, 0.f); sa1 += fmaxf(e1, 0.f);
        c0 += (int)__popcll(__ballot(e0 > 0.f));
        c1 += (int)__popcll(__ballot(e1 > 0.f));
      }
  };

  // t = m - div(ux,uy); reads buf0 halos, writes t halos to buf1
  auto div_pass = [&]() {
#pragma unroll
    for (int di = 0; di < TI; ++di) {
      const int i = i0 + di;
#pragma unroll
      for (int dj = 0; dj < TJ; ++dj) {
        const int j = j0 + dj;
        float up, lf;
        if (di > 0) up = ux[di - 1][dj];
        else { float h = sTop[0][dj][(ty > 0) ? ty - 1 : 0][tx]; up = (ty > 0) ? h : 0.f; }
        if (dj > 0) lf = uy[di][dj - 1];
        else { float h = sLeft[0][di][ty][(tx > 0) ? tx - 1 : 0]; lf = (tx > 0) ? h : 0.f; }
        float vx = (i == NN - 1) ? 0.f : ux[di][dj];
        float vy = (j == NN - 1) ? 0.f : uy[di][dj];
        float tt = m[di][dj] - ((vx - up) + (vy - lf));
        t[di][dj] = tt;
        if (di == 0) sTop[1][dj][ty][tx] = tt;
        if (dj == 0) sLeft[1][di][ty][tx] = tt;
      }
    }
  };

  // reads buf1 halos; consume(di,dj,gx,gy) with (gx,gy)=grad(t)
  auto grad_pass = [&](auto&& consume) {
#pragma unroll
    for (int di = 0; di < TI; ++di) {
      const int i = i0 + di;
#pragma unroll
      for (int dj = 0; dj < TJ; ++dj) {
        const int j = j0 + dj;
        float dn, rt;
        if (di < TI - 1) dn = t[di + 1][dj];
        else dn = sTop[1][dj][(ty < GI - 1) ? ty + 1 : ty][tx];
        if (dj < TJ - 1) rt = t[di][dj + 1];
        else rt = sLeft[1][di][ty][(tx < GJ - 1) ? tx + 1 : tx];
        float gx = (i == NN - 1) ? 0.f : dn - t[di][dj];
        float gy = (j == NN - 1) ? 0.f : rt - t[di][dj];
        consume(di, dj, gx, gy);
      }
    }
  };

  float A = 0.f;
  // P1 carry: sums + probe results produced at previous P4b
  float S0p = 0.f, S1p = 0.f, p1sa0 = 0.f, p1sa1 = 0.f, p1c0 = 0.f, p1c1 = 0.f;
  float t1p0 = 0.f, t1p1 = 0.f;
  float h1x = 0.f, h1y = 0.f, h3x = 0.f, h3y = 0.f;  // previous thresholds
  const float rad3 = r * (MUc * 0.5f);

#pragma unroll 1
  for (int it = 0; it < NIT; ++it) {
    const float a_ = 0.5f * (MUc + sqrtf(MUc * (MUc + 4.f * A)));
    float thx, thy;
    if (it == 0) { thx = INFINITY; thy = INFINITY; }
    else {
      float2 th = solve2(scanP1, S0p, S1p, r * A, p1sa0, p1c0, t1p0, p1sa1, p1c1, t1p1);
      thx = th.x; thy = th.y;
      h1x = thx; h1y = thy;
    }

    // P2a: y = cu*u + cv*clamp(u-xi, ±th); write y halos (buf0)
    {
      const float inv = 1.f / (A + a_);
      const float cu = A * inv, cv = a_ * inv;
#pragma unroll
      for (int di = 0; di < TI; ++di)
#pragma unroll
        for (int dj = 0; dj < TJ; ++dj) {
          float vx = fminf(fmaxf(ux[di][dj] - xx[di][dj], -thx), thx);
          float vy = fminf(fmaxf(uy[di][dj] - xy[di][dj], -thy), thy);
          ux[di][dj] = ux[di][dj] * cu + vx * cv;
          uy[di][dj] = uy[di][dj] * cu + vy * cv;
        }
#pragma unroll
      for (int dj = 0; dj < TJ; ++dj) sTop[0][dj][ty][tx] = ux[TI - 1][dj];
#pragma unroll
      for (int di = 0; di < TI; ++di) sLeft[0][di][ty][tx] = uy[di][TJ - 1];
    }
    __syncthreads();
    div_pass();            // t = M - div(y)
    __syncthreads();

    // P2b: u_pre = y - (mu/2) grad(t); fused S3 sums + P3 probe at prev theta3
    const float t3p0 = fmaxf(0.f, h3x);
    const float t3p1 = fmaxf(0.f, h3y);
    {
      float s0 = 0.f, s1 = 0.f, p0 = 0.f, p1v = 0.f; int c0 = 0, c1 = 0;
      grad_pass([&](int di, int dj, float gx, float gy) {
        float nux = ux[di][dj] - 0.125f * gx;
        float nuy = uy[di][dj] - 0.125f * gy;
        ux[di][dj] = nux; uy[di][dj] = nuy;
        float a0 = fabsf(nux), a1 = fabsf(nuy);
        s0 += a0; s1 += a1;
        float e0 = a0 - t3p0, e1 = a1 - t3p1;
        p0 += fmaxf(e0, 0.f); p1v += fmaxf(e1, 0.f);
        c0 += (int)__popcll(__ballot(e0 > 0.f));
        c1 += (int)__popcll(__ballot(e1 > 0.f));
      });
      float4 q4; float2 q2;
      redF4C2(s0, s1, p0, p1v, c0, c1, q4, q2);
      float2 th3 = solve2(scanP3, q4.x, q4.y, rad3, q4.z, q2.x, t3p0, q4.w, q2.y, t3p1);
      h3x = th3.x; h3y = th3.y;
      // P4a: u = clamp(u_pre, ±th3); write u halos (buf0)
#pragma unroll
      for (int di = 0; di < TI; ++di)
#pragma unroll
        for (int dj = 0; dj < TJ; ++dj) {
          ux[di][dj] = fminf(fmaxf(ux[di][dj], -th3.x), th3.x);
          uy[di][dj] = fminf(fmaxf(uy[di][dj], -th3.y), th3.y);
        }
#pragma unroll
      for (int dj = 0; dj < TJ; ++dj) sTop[0][dj][ty][tx] = ux[TI - 1][dj];
#pragma unroll
      for (int di = 0; di < TI; ++di) sLeft[0][di][ty][tx] = uy[di][TJ - 1];
    }
    __syncthreads();
    div_pass();            // t = Mnew
    __syncthreads();

    // P4b: xi += a*grad(Mnew); fused next-P1 sums + probe at prev theta1
    t1p0 = fmaxf(0.f, h1x);
    t1p1 = fmaxf(0.f, h1y);
    {
      float s0 = 0.f, s1 = 0.f, p0 = 0.f, p1v = 0.f; int c0 = 0, c1 = 0;
      grad_pass([&](int di, int dj, float gx, float gy) {
        xx[di][dj] += a_ * gx;
        xy[di][dj] += a_ * gy;
        float awx = fabsf(ux[di][dj] - xx[di][dj]);
        float awy = fabsf(uy[di][dj] - xy[di][dj]);
        s0 += awx; s1 += awy;
        float e0 = awx - t1p0, e1 = awy - t1p1;
        p0 += fmaxf(e0, 0.f); p1v += fmaxf(e1, 0.f);
        c0 += (int)__popcll(__ballot(e0 > 0.f));
        c1 += (int)__popcll(__ballot(e1 > 0.f));
      });
      float4 q4; float2 q2;
      redF4C2(s0, s1, p0, p1v, c0, c1, q4, q2);
      S0p = q4.x; S1p = q4.y; p1sa0 = q4.z; p1sa1 = q4.w; p1c0 = q2.x; p1c1 = q2.y;
    }
    A += a_;
  }

  // outputs: M1 = last Mnew (in t), u interleaved (last-dim 2)
  float* outM = out + (size_t)b * NN * NN;
  float* outU = out + (size_t)Nb * NN * NN + (size_t)b * NN * NN * 2;
#pragma unroll
  for (int di = 0; di < TI; ++di)
#pragma unroll
    for (int dj = 0; dj < TJ; ++dj) {
      const int idx = (i0 + di) * NN + (j0 + dj);
      outM[idx] = t[di][dj];
      reinterpret_cast<float2*>(outU)[idx] = make_float2(ux[di][dj], uy[di][dj]);
    }
}

extern "C" void kernel_launch(void* const* d_in, const int* in_sizes, int n_in,
                              void* d_out, int out_size, void* d_ws, size_t ws_size,
                              hipStream_t stream) {
  const float* M  = (const float*)d_in[0];
  const float* tv = (const float*)d_in[1];
  const int Nb = in_sizes[0] / (NN * NN);   // 8
  tv_kernel<<<dim3(Nb), dim3(NTHREADS), 0, stream>>>(M, tv, (float*)d_out, Nb);
}

// Round 5
// 4474.962 us; speedup vs baseline: 2.4854x; 1.2902x over previous
//
#include <hip/hip_runtime.h>
#include <math.h>

#define NIT 200
#define NN 128
#define TI 4
#define TJ 8
#define GI 32   // NN/TI
#define GJ 16   // NN/TJ
#define NTHREADS 512
#define NWAVES 8

__global__ __attribute__((amdgpu_flat_work_group_size(NTHREADS, NTHREADS),
                          amdgpu_waves_per_eu(2, 2)))
void tv_kernel(const float* __restrict__ Min, const float* __restrict__ tvr,
               float* __restrict__ out, int Nb)
{
  const float MUc = 0.25f;
  const int b   = blockIdx.x;
  const int tid = threadIdx.x;
  const int tx  = tid & (GJ - 1);   // 0..15
  const int ty  = tid >> 4;         // 0..31
  const int lane = tid & 63;
  const int wv   = tid >> 6;
  const int i0 = ty * TI;
  const int j0 = tx * TJ;

  // Conflict-free halo buffers: addr/4 = comp*512 + ty*16 + tx -> bank = lane%32 (2-way, free).
  __shared__ float sTopW [2][TJ][GI][GJ];   // 32 KB
  __shared__ float sLeftW[2][TI][GI][GJ];   // 16 KB
  __shared__ float4 sRed[2][NWAVES];        // parity-buffered reduction scratch
  // Occupancy clamp: push LDS past 80 KB so max 1 block/CU -> compiler targets
  // 2 waves/EU -> 256 arch-VGPR budget (state fits, no AGPR churn). Grid is
  // 8 blocks on 256 CUs, so this costs nothing at runtime.
  __shared__ float lds_pad[8704];           // 34 KB -> total ~82.3 KB

  const float r = tvr[0];
  if (r == -1.2345e30f) lds_pad[tid] = 1.f;  // opaque keep-alive (never true)

  // register state: 6 arrays x 32 = 192 floats
  float m[TI][TJ], ux[TI][TJ], uy[TI][TJ], xx[TI][TJ], xy[TI][TJ], t[TI][TJ];

  const float* Mb = Min + (size_t)b * NN * NN;
#pragma unroll
  for (int di = 0; di < TI; ++di) {
    float4 v0 = *reinterpret_cast<const float4*>(Mb + (i0 + di) * NN + j0);
    float4 v1 = *reinterpret_cast<const float4*>(Mb + (i0 + di) * NN + j0 + 4);
    m[di][0] = v0.x; m[di][1] = v0.y; m[di][2] = v0.z; m[di][3] = v0.w;
    m[di][4] = v1.x; m[di][5] = v1.y; m[di][6] = v1.z; m[di][7] = v1.w;
#pragma unroll
    for (int dj = 0; dj < TJ; ++dj) {
      ux[di][dj] = 0.f; uy[di][dj] = 0.f;
      xx[di][dj] = 0.f; xy[di][dj] = 0.f;
      t[di][dj] = 0.f;
    }
  }

  int par = 0;
  auto blk_red4 = [&](float v0, float v1, float v2, float v3) {
#pragma unroll
    for (int off = 32; off >= 1; off >>= 1) {
      v0 += __shfl_xor(v0, off, 64);
      v1 += __shfl_xor(v1, off, 64);
      v2 += __shfl_xor(v2, off, 64);
      v3 += __shfl_xor(v3, off, 64);
    }
    if (lane == 0) sRed[par][wv] = make_float4(v0, v1, v2, v3);
    __syncthreads();
    float4 acc = make_float4(0.f, 0.f, 0.f, 0.f);
#pragma unroll
    for (int w = 0; w < NWAVES; ++w) {
      float4 q = sRed[par][w];
      acc.x += q.x; acc.y += q.y; acc.z += q.z; acc.w += q.w;
    }
    par ^= 1;
    return acc;
  };
  auto blk_red2 = [&](float v0, float v1) {
#pragma unroll
    for (int off = 32; off >= 1; off >>= 1) {
      v0 += __shfl_xor(v0, off, 64);
      v1 += __shfl_xor(v1, off, 64);
    }
    if (lane == 0) sRed[par][wv] = make_float4(v0, v1, 0.f, 0.f);
    __syncthreads();
    float a0 = 0.f, a1 = 0.f;
#pragma unroll
    for (int w = 0; w < NWAVES; ++w) {
      float4 q = sRed[par][w];
      a0 += q.x; a1 += q.y;
    }
    par ^= 1;
    return make_float2(a0, a1);
  };

  // Newton for the two per-component thresholds. S0/S1 precomputed L1 sums.
  // getabs(di,dj,a0,a1) yields per-element magnitudes. Exact Duchi root:
  // terminates on fixed point (tn==t) or segment stability (equal counts).
  auto newton_rounds = [&](auto getabs, float S0, float S1, float rad,
                           float& wsx, float& wsy, float& oxv, float& oyv) {
    const float invD = 1.f / 16384.f;
    float t0, t1; bool d0 = false, d1 = false;
    if (S0 <= rad) { t0 = 0.f; d0 = true; }
    else { t0 = (S0 - rad) * invD; t0 = fmaxf(t0, wsx); }
    if (S1 <= rad) { t1 = 0.f; d1 = true; }
    else { t1 = (S1 - rad) * invD; t1 = fmaxf(t1, wsy); }
    float np0 = -1.f, np1 = -1.f;
    for (int k = 0; k < 40 && !(d0 && d1); ++k) {
      float sa0 = 0.f, c0 = 0.f, sa1 = 0.f, c1 = 0.f;
#pragma unroll
      for (int di = 0; di < TI; ++di)
#pragma unroll
        for (int dj = 0; dj < TJ; ++dj) {
          float a0v, a1v; getabs(di, dj, a0v, a1v);
          if (a0v > t0) { sa0 += a0v; c0 += 1.f; }
          if (a1v > t1) { sa1 += a1v; c1 += 1.f; }
        }
      float4 rd = blk_red4(sa0, c0, sa1, c1);
      if (!d0) {
        if (rd.y < 0.5f) { t0 = (S0 - rad) * invD; np0 = -1.f; }
        else {
          float tn = __fdividef(rd.x - rad, rd.y);
          if (rd.y == np0 || tn == t0) d0 = true;
          t0 = tn; np0 = rd.y;
        }
      }
      if (!d1) {
        if (rd.w < 0.5f) { t1 = (S1 - rad) * invD; np1 = -1.f; }
        else {
          float tn = __fdividef(rd.z - rad, rd.w);
          if (rd.w == np1 || tn == t1) d1 = true;
          t1 = tn; np1 = rd.w;
        }
      }
    }
    oxv = t0; oyv = t1; wsx = t0; wsy = t1;
  };

  // div pass: t = m - div(ux,uy); reads buf0 halos, writes t-halos to buf1.
  auto div_pass = [&]() {
#pragma unroll
    for (int di = 0; di < TI; ++di) {
      const int i = i0 + di;
#pragma unroll
      for (int dj = 0; dj < TJ; ++dj) {
        const int j = j0 + dj;
        float up, lf;
        if (di > 0) up = ux[di - 1][dj];
        else { float h = sTopW[0][dj][(ty > 0) ? ty - 1 : 0][tx]; up = (ty > 0) ? h : 0.f; }
        if (dj > 0) lf = uy[di][dj - 1];
        else { float h = sLeftW[0][di][ty][(tx > 0) ? tx - 1 : 0]; lf = (tx > 0) ? h : 0.f; }
        float vxv = (i == NN - 1) ? 0.f : ux[di][dj];
        float vyv = (j == NN - 1) ? 0.f : uy[di][dj];
        float tt = m[di][dj] - ((vxv - up) + (vyv - lf));
        t[di][dj] = tt;
        if (di == 0) sTopW[1][dj][ty][tx] = tt;
        if (dj == 0) sLeftW[1][di][ty][tx] = tt;
      }
    }
  };

  // grad pass: reads buf1 halos; consume(di,dj,gx,gy) with (gx,gy)=grad(t).
  auto grad_pass = [&](auto&& consume) {
#pragma unroll
    for (int di = 0; di < TI; ++di) {
      const int i = i0 + di;
#pragma unroll
      for (int dj = 0; dj < TJ; ++dj) {
        const int j = j0 + dj;
        float dn, rt;
        if (di < TI - 1) dn = t[di + 1][dj];
        else dn = sTopW[1][dj][(ty < GI - 1) ? ty + 1 : ty][tx];
        if (dj < TJ - 1) rt = t[di][dj + 1];
        else rt = sLeftW[1][di][ty][(tx < GJ - 1) ? tx + 1 : tx];
        float gx = (i == NN - 1) ? 0.f : dn - t[di][dj];
        float gy = (j == NN - 1) ? 0.f : rt - t[di][dj];
        consume(di, dj, gx, gy);
      }
    }
  };

  float A = 0.f;
  float w1x = -1.f, w1y = -1.f, w3x = -1.f, w3y = -1.f;  // warm starts
  float S0p = 0.f, S1p = 0.f;   // fused P1 sums (|u - xi|) from prev P4b
  float thx, thy;
  const float rad3 = r * (MUc * 0.5f);

#pragma unroll 1
  for (int it = 0; it < NIT; ++it) {
    const float a_ = 0.5f * (MUc + sqrtf(MUc * (MUc + 4.f * A)));

    // ---- P1 thresholds (A==0 at it==0 -> radius 0 -> identity)
    if (it == 0) { thx = INFINITY; thy = INFINITY; }
    else newton_rounds([&](int di, int dj, float& a0v, float& a1v) {
                         a0v = fabsf(ux[di][dj] - xx[di][dj]);
                         a1v = fabsf(uy[di][dj] - xy[di][dj]);
                       }, S0p, S1p, r * A, w1x, w1y, thx, thy);

    // ---- P2a: y = cu*u + cv*clamp(u-xi, ±th); write y halos (buf0)
    {
      const float inv = 1.f / (A + a_);
      const float cu = A * inv, cv = a_ * inv;
#pragma unroll
      for (int di = 0; di < TI; ++di)
#pragma unroll
        for (int dj = 0; dj < TJ; ++dj) {
          float vx = fminf(fmaxf(ux[di][dj] - xx[di][dj], -thx), thx);
          float vy = fminf(fmaxf(uy[di][dj] - xy[di][dj], -thy), thy);
          ux[di][dj] = ux[di][dj] * cu + vx * cv;
          uy[di][dj] = uy[di][dj] * cu + vy * cv;
        }
#pragma unroll
      for (int dj = 0; dj < TJ; ++dj) sTopW[0][dj][ty][tx] = ux[TI - 1][dj];
#pragma unroll
      for (int di = 0; di < TI; ++di) sLeftW[0][di][ty][tx] = uy[di][TJ - 1];
    }
    __syncthreads();
    div_pass();            // t = M - div(y)
    __syncthreads();

    // ---- P2b: u_pre = y - (mu/2) grad(t); fused P3 L1-sums
    {
      float s0 = 0.f, s1 = 0.f;
      grad_pass([&](int di, int dj, float gx, float gy) {
        float nux = ux[di][dj] - 0.125f * gx;
        float nuy = uy[di][dj] - 0.125f * gy;
        ux[di][dj] = nux; uy[di][dj] = nuy;
        s0 += fabsf(nux);
        s1 += fabsf(nuy);
      });
      float2 S3 = blk_red2(s0, s1);

      // ---- P3: u = clamp(u_pre, ±th3)
      newton_rounds([&](int di, int dj, float& a0v, float& a1v) {
                      a0v = fabsf(ux[di][dj]); a1v = fabsf(uy[di][dj]);
                    }, S3.x, S3.y, rad3, w3x, w3y, thx, thy);
    }
    // ---- P4a: apply clamp; write u halos (buf0)
#pragma unroll
    for (int di = 0; di < TI; ++di)
#pragma unroll
      for (int dj = 0; dj < TJ; ++dj) {
        ux[di][dj] = fminf(fmaxf(ux[di][dj], -thx), thx);
        uy[di][dj] = fminf(fmaxf(uy[di][dj], -thy), thy);
      }
#pragma unroll
    for (int dj = 0; dj < TJ; ++dj) sTopW[0][dj][ty][tx] = ux[TI - 1][dj];
#pragma unroll
    for (int di = 0; di < TI; ++di) sLeftW[0][di][ty][tx] = uy[di][TJ - 1];
    __syncthreads();
    div_pass();            // t = Mnew
    __syncthreads();

    // ---- P4b: xi += a*grad(Mnew); fused next-P1 L1-sums
    {
      float s0 = 0.f, s1 = 0.f;
      grad_pass([&](int di, int dj, float gx, float gy) {
        xx[di][dj] += a_ * gx;
        xy[di][dj] += a_ * gy;
        s0 += fabsf(ux[di][dj] - xx[di][dj]);
        s1 += fabsf(uy[di][dj] - xy[di][dj]);
      });
      float2 SP = blk_red2(s0, s1);
      S0p = SP.x; S1p = SP.y;
    }
    A += a_;
  }

  // outputs: M1 = last Mnew (in t), u interleaved (last-dim 2)
  float* outM = out + (size_t)b * NN * NN;
  float* outU = out + (size_t)Nb * NN * NN + (size_t)b * NN * NN * 2;
#pragma unroll
  for (int di = 0; di < TI; ++di)
#pragma unroll
    for (int dj = 0; dj < TJ; ++dj) {
      const int idx = (i0 + di) * NN + (j0 + dj);
      outM[idx] = t[di][dj];
      reinterpret_cast<float2*>(outU)[idx] = make_float2(ux[di][dj], uy[di][dj]);
    }
}

extern "C" void kernel_launch(void* const* d_in, const int* in_sizes, int n_in,
                              void* d_out, int out_size, void* d_ws, size_t ws_size,
                              hipStream_t stream) {
  const float* M  = (const float*)d_in[0];
  const float* tv = (const float*)d_in[1];
  const int Nb = in_sizes[0] / (NN * NN);   // 8
  tv_kernel<<<dim3(Nb), dim3(NTHREADS), 0, stream>>>(M, tv, (float*)d_out, Nb);
}